// Round 7
// baseline (178.201 us; speedup 1.0000x reference)
//
#include <hip/hip_runtime.h>

#define BATCH 8
#define GDIM 32
#define NCELL (GDIM * GDIM * GDIM)   // 32768
#define NG (2 * BATCH)               // 16 grids
#define PA_QPB 16                    // phase-A queries per block (16 lanes each)
#define NB_B 2048                    // phase-B blocks

// ---------------- helpers ----------------
__device__ __forceinline__ void gridParams(const float* bb, float lo[3],
                                           float inv[3], float cs[3]) {
#pragma unroll
    for (int d = 0; d < 3; ++d) {
        lo[d] = bb[d];
        float span = bb[3 + d] - bb[d];
        float iv = (float)GDIM / (span * (1.f + 1e-6f) + 1e-12f);
        inv[d] = iv;
        cs[d] = 1.f / iv;
    }
}

__device__ __forceinline__ int cellOf(float v, float lo, float inv) {
    return min(max((int)floorf((v - lo) * inv), 0), GDIM - 1);
}

__device__ __forceinline__ float axd(float v, float c0, float cw) {
    return fmaxf(fmaxf(c0 - v, v - (c0 + cw)), 0.f);
}

__device__ __forceinline__ void get4pts(const float4& f0, const float4& f1,
                                        const float4& f2, float px[4],
                                        float py[4], float pz[4]) {
    px[0] = f0.x; py[0] = f0.y; pz[0] = f0.z;
    px[1] = f0.w; py[1] = f1.x; pz[1] = f1.y;
    px[2] = f1.z; py[2] = f1.w; pz[2] = f2.x;
    px[3] = f2.y; py[3] = f2.z; pz[3] = f2.w;
}

// ---------------- k1: bbox (blocks 0..NG-1) + zero cnt (rest) + zero wcount ----------------
__global__ __launch_bounds__(256) void k1_bbox_zero(
    const float* __restrict__ ytrue, const float* __restrict__ ypred,
    int N, float* __restrict__ bbox, uint4* __restrict__ cntz,
    unsigned* __restrict__ wcount)
{
    if (blockIdx.x == 0 && threadIdx.x == 0) *wcount = 0u;
    if (blockIdx.x >= NG) {
        cntz[(blockIdx.x - NG) * 256 + threadIdx.x] = make_uint4(0, 0, 0, 0);
        return;
    }
    int g = blockIdx.x;
    int cloud = g >> 3, b = g & 7;
    const float4* src4 = (const float4*)((cloud ? ypred : ytrue) + (size_t)b * N * 3);
    int nquad = N >> 2;
    float mn[3] = {1e30f, 1e30f, 1e30f}, mx[3] = {-1e30f, -1e30f, -1e30f};
    for (int qk = threadIdx.x; qk < nquad; qk += 256) {
        float4 f0 = src4[3 * qk], f1 = src4[3 * qk + 1], f2 = src4[3 * qk + 2];
        float px[4], py[4], pz[4];
        get4pts(f0, f1, f2, px, py, pz);
#pragma unroll
        for (int k = 0; k < 4; ++k) {
            mn[0] = fminf(mn[0], px[k]); mx[0] = fmaxf(mx[0], px[k]);
            mn[1] = fminf(mn[1], py[k]); mx[1] = fmaxf(mx[1], py[k]);
            mn[2] = fminf(mn[2], pz[k]); mx[2] = fmaxf(mx[2], pz[k]);
        }
    }
#pragma unroll
    for (int o = 32; o; o >>= 1) {
#pragma unroll
        for (int d = 0; d < 3; ++d) {
            mn[d] = fminf(mn[d], __shfl_down(mn[d], o, 64));
            mx[d] = fmaxf(mx[d], __shfl_down(mx[d], o, 64));
        }
    }
    __shared__ float sm[6][4];
    int w = threadIdx.x >> 6, l = threadIdx.x & 63;
    if (l == 0) {
#pragma unroll
        for (int d = 0; d < 3; ++d) { sm[d][w] = mn[d]; sm[3 + d][w] = mx[d]; }
    }
    __syncthreads();
    if (threadIdx.x == 0) {
#pragma unroll
        for (int k = 0; k < 6; ++k) {
            float v = sm[k][0];
#pragma unroll
            for (int i = 1; i < 4; ++i)
                v = (k < 3) ? fminf(v, sm[k][i]) : fmaxf(v, sm[k][i]);
            bbox[g * 6 + k] = v;
        }
    }
}

// ---------------- k2: histogram ----------------
__global__ __launch_bounds__(256) void k2_hist(
    const float* __restrict__ ytrue, const float* __restrict__ ypred,
    int N, const float* __restrict__ bbox, unsigned* __restrict__ cnt)
{
    int nquad = N >> 2;
    int bpg = nquad >> 8;
    int g = blockIdx.x / bpg;
    int qk = (blockIdx.x - g * bpg) * 256 + threadIdx.x;
    int cloud = g >> 3, b = g & 7;
    const float4* src4 = (const float4*)((cloud ? ypred : ytrue) + (size_t)b * N * 3);
    float lo[3], inv[3], cs[3];
    gridParams(bbox + g * 6, lo, inv, cs);
    float4 f0 = src4[3 * qk], f1 = src4[3 * qk + 1], f2 = src4[3 * qk + 2];
    float px[4], py[4], pz[4];
    get4pts(f0, f1, f2, px, py, pz);
    unsigned* Cg = cnt + (size_t)g * NCELL;
#pragma unroll
    for (int k = 0; k < 4; ++k) {
        int cx = cellOf(px[k], lo[0], inv[0]);
        int cy = cellOf(py[k], lo[1], inv[1]);
        int cz = cellOf(pz[k], lo[2], inv[2]);
        atomicAdd(&Cg[(cz * GDIM + cy) * GDIM + cx], 1u);
    }
}

// ---------------- k3: per-grid scan, pack (start<<16)|cnt, zero fill ----------------
__global__ __launch_bounds__(1024) void k3_scan(
    unsigned* __restrict__ cnt, unsigned* __restrict__ sc)
{
    int g = blockIdx.x;
    unsigned* c = cnt + (size_t)g * NCELL;
    unsigned* out = sc + (size_t)g * NCELL;
    int t = threadIdx.x;
    uint4 v[8];
    const uint4* c4 = (const uint4*)(c + t * 32);
    unsigned sum = 0;
#pragma unroll
    for (int j = 0; j < 8; ++j) {
        v[j] = c4[j];
        sum += v[j].x + v[j].y + v[j].z + v[j].w;
    }
    __shared__ unsigned sd[1024];
    sd[t] = sum;
    __syncthreads();
    unsigned val = sum;
    for (int off = 1; off < 1024; off <<= 1) {
        unsigned o = (t >= off) ? sd[t - off] : 0u;
        __syncthreads();
        val += o;
        sd[t] = val;
        __syncthreads();
    }
    unsigned run = val - sum;
    uint4* o4 = (uint4*)(out + t * 32);
    uint4* z4 = (uint4*)(c + t * 32);
#pragma unroll
    for (int j = 0; j < 8; ++j) {
        uint4 w;
        w.x = (run << 16) | v[j].x; run += v[j].x;
        w.y = (run << 16) | v[j].y; run += v[j].y;
        w.z = (run << 16) | v[j].z; run += v[j].z;
        w.w = (run << 16) | v[j].w; run += v[j].w;
        o4[j] = w;
        z4[j] = make_uint4(0, 0, 0, 0);
    }
}

// ---------------- k4: scatter ----------------
__global__ __launch_bounds__(256) void k4_scatter(
    const float* __restrict__ ytrue, const float* __restrict__ ypred,
    int N, const float* __restrict__ bbox, const unsigned* __restrict__ sc,
    unsigned* __restrict__ fill, float4* __restrict__ sorted)
{
    int nquad = N >> 2;
    int bpg = nquad >> 8;
    int g = blockIdx.x / bpg;
    int qk = (blockIdx.x - g * bpg) * 256 + threadIdx.x;
    int cloud = g >> 3, b = g & 7;
    const float4* src4 = (const float4*)((cloud ? ypred : ytrue) + (size_t)b * N * 3);
    float lo[3], inv[3], cs[3];
    gridParams(bbox + g * 6, lo, inv, cs);
    float4 f0 = src4[3 * qk], f1 = src4[3 * qk + 1], f2 = src4[3 * qk + 2];
    float px[4], py[4], pz[4];
    get4pts(f0, f1, f2, px, py, pz);
    const unsigned* Sg = sc + (size_t)g * NCELL;
    unsigned* Fg = fill + (size_t)g * NCELL;
    float4* Og = sorted + (size_t)g * N;
#pragma unroll
    for (int k = 0; k < 4; ++k) {
        int cx = cellOf(px[k], lo[0], inv[0]);
        int cy = cellOf(py[k], lo[1], inv[1]);
        int cz = cellOf(pz[k], lo[2], inv[2]);
        int cid = (cz * GDIM + cy) * GDIM + cx;
        unsigned pos = (Sg[cid] >> 16) + atomicAdd(&Fg[cid], 1u);
        Og[pos] = make_float4(px[k], py[k], pz[k],
                              fmaf(px[k], px[k], fmaf(py[k], py[k], pz[k] * pz[k])));
    }
}

// ---------------- k5a: phase A — one query per 16-lane group, ±1 box only ----------------
__global__ __launch_bounds__(256) void k5a(
    const float4* __restrict__ sorted, const unsigned* __restrict__ sc,
    const float* __restrict__ bbox, int N, double* __restrict__ partialA,
    uint2* __restrict__ wlist, unsigned* __restrict__ wcount)
{
    const int lane = threadIdx.x & 63;
    const int wid = threadIdx.x >> 6;
    const int s = threadIdx.x & 15;           // sublane within group
    const int grp = threadIdx.x >> 4;         // 0..15 groups per block
    int qglobal = (int)blockIdx.x * PA_QPB + grp;
    int g = qglobal / N;
    int qi = qglobal - g * N;
    int cloud = g >> 3, b = g & 7;
    int gr = ((1 - cloud) << 3) | b;

    float lo[3], inv[3], cs[3];
    gridParams(bbox + gr * 6, lo, inv, cs);
    const unsigned* __restrict__ C = sc + (size_t)gr * NCELL;
    const float4* __restrict__ P = sorted + (size_t)gr * N;

    float4 q = sorted[(size_t)g * N + qi];    // broadcast within group
    float q2 = q.w;
    float nqx = -2.f * q.x, nqy = -2.f * q.y, nqz = -2.f * q.z;
    float tb = 1e30f;

    int cx = cellOf(q.x, lo[0], inv[0]);
    int cy = cellOf(q.y, lo[1], inv[1]);
    int cz = cellOf(q.z, lo[2], inv[2]);

#pragma unroll
    for (int bat = 0; bat < 2; ++bat) {
        int c = s + bat * 16;
        unsigned cn = 0, st = 0;
        if (c < 27) {
            int dx = c % 3 - 1, dy = (c / 3) % 3 - 1, dz = c / 9 - 1;
            int xx = cx + dx, yy = cy + dy, zz = cz + dz;
            if (xx >= 0 && xx < GDIM && yy >= 0 && yy < GDIM &&
                zz >= 0 && zz < GDIM) {
                unsigned h = C[(zz * GDIM + yy) * GDIM + xx];
                st = h >> 16;
                cn = h & 0xffffu;
            }
        }
        unsigned mc = cn;
#pragma unroll
        for (int o = 1; o < 16; o <<= 1)
            mc = max(mc, (unsigned)__shfl_xor((int)mc, o, 16));
#pragma unroll 4
        for (unsigned j = 0; j < mc; ++j) {
            if (j < cn) {
                float4 p = P[st + j];
                float t = fmaf(nqx, p.x, fmaf(nqy, p.y, fmaf(nqz, p.z, p.w)));
                tb = fminf(tb, t);
            }
        }
    }
#pragma unroll
    for (int o = 1; o < 16; o <<= 1)
        tb = fminf(tb, __shfl_xor(tb, o, 16));
    float d2 = fmaxf(0.f, q2 + tb);

    int x0 = max(cx - 1, 0), x1 = min(cx + 1, GDIM - 1);
    int y0 = max(cy - 1, 0), y1 = min(cy + 1, GDIM - 1);
    int z0 = max(cz - 1, 0), z1 = min(cz + 1, GDIM - 1);
    float mx = fminf(x0 > 0 ? q.x - (lo[0] + x0 * cs[0]) : 1e30f,
                     x1 < GDIM - 1 ? (lo[0] + (x1 + 1) * cs[0]) - q.x : 1e30f);
    float my = fminf(y0 > 0 ? q.y - (lo[1] + y0 * cs[1]) : 1e30f,
                     y1 < GDIM - 1 ? (lo[1] + (y1 + 1) * cs[1]) - q.y : 1e30f);
    float mz = fminf(z0 > 0 ? q.z - (lo[2] + z0 * cs[2]) : 1e30f,
                     z1 < GDIM - 1 ? (lo[2] + (z1 + 1) * cs[2]) - q.z : 1e30f);
    float m = fminf(mx, fminf(my, mz));
    bool done = (m > 0.f) && (m * m * 0.999f >= d2);

    double val = 0.0;
    if (s == 0) {
        if (done) {
            val = (double)d2;
        } else {
            unsigned idx = atomicAdd(wcount, 1u);
            wlist[idx] = make_uint2((unsigned)qglobal, __float_as_uint(tb));
        }
    }
#pragma unroll
    for (int o = 32; o; o >>= 1) val += __shfl_down(val, o, 64);
    __shared__ double sd[4];
    if (lane == 0) sd[wid] = val;
    __syncthreads();
    if (threadIdx.x == 0)
        partialA[blockIdx.x] = sd[0] + sd[1] + sd[2] + sd[3];
}

// ---------------- k5b: phase B — one query per wave, shell expansion r>=2 ----------------
__global__ __launch_bounds__(256) void k5b(
    const float4* __restrict__ sorted, const unsigned* __restrict__ sc,
    const float* __restrict__ bbox, int N, const uint2* __restrict__ wlist,
    const unsigned* __restrict__ wcount, double* __restrict__ partialB)
{
    const int lane = threadIdx.x & 63;
    const int wid = threadIdx.x >> 6;
    int W = (int)blockIdx.x * 4 + wid;
    int nW = (int)gridDim.x * 4;
    unsigned count = *wcount;
    double acc = 0.0;

    for (unsigned wi = (unsigned)W; wi < count; wi += (unsigned)nW) {
        uint2 e = wlist[wi];
        int qglobal = (int)e.x;
        float tb = __uint_as_float(e.y);
        int g = qglobal / N;
        int qi = qglobal - g * N;
        int cloud = g >> 3, b = g & 7;
        int gr = ((1 - cloud) << 3) | b;

        float lo[3], inv[3], cs[3];
        gridParams(bbox + gr * 6, lo, inv, cs);
        const unsigned* __restrict__ C = sc + (size_t)gr * NCELL;
        const float4* __restrict__ P = sorted + (size_t)gr * N;

        float4 q = sorted[(size_t)g * N + qi];
        float q2 = q.w;
        float nqx = -2.f * q.x, nqy = -2.f * q.y, nqz = -2.f * q.z;
        int cx = cellOf(q.x, lo[0], inv[0]);
        int cy = cellOf(q.y, lo[1], inv[1]);
        int cz = cellOf(q.z, lo[2], inv[2]);
        float d2cur = q2 + tb;

        for (int r = 2;; ++r) {
            int L = 2 * r + 1;
            int S = L * L;
            int ring = 8 * r;
            int scnt = 2 * S + (2 * r - 1) * ring;
            for (int s0 = 0; s0 < scnt; s0 += 64) {
                int si = s0 + lane;
                unsigned cn = 0, st = 0;
                if (si < scnt) {
                    int dx, dy, dz;
                    if (si < S) {
                        dz = -r; dx = si % L - r; dy = si / L - r;
                    } else if (si < 2 * S) {
                        int t = si - S;
                        dz = r; dx = t % L - r; dy = t / L - r;
                    } else {
                        int rem = si - 2 * S;
                        int lvl = rem / ring;
                        dz = -r + 1 + lvl;
                        int pos = rem - lvl * ring;
                        int side = pos / (2 * r);
                        int o = pos - side * 2 * r;
                        if (side == 0)      { dy = -r; dx = -r + o; }
                        else if (side == 1) { dx = r;  dy = -r + o; }
                        else if (side == 2) { dy = r;  dx = r - o; }
                        else                { dx = -r; dy = r - o; }
                    }
                    int xx = cx + dx, yy = cy + dy, zz = cz + dz;
                    if (xx >= 0 && xx < GDIM && yy >= 0 && yy < GDIM &&
                        zz >= 0 && zz < GDIM) {
                        float ddx = axd(q.x, lo[0] + xx * cs[0], cs[0]);
                        float ddy = axd(q.y, lo[1] + yy * cs[1], cs[1]);
                        float ddz = axd(q.z, lo[2] + zz * cs[2], cs[2]);
                        float lb2 = fmaf(ddx, ddx, fmaf(ddy, ddy, ddz * ddz));
                        if (lb2 * 0.999f < d2cur) {
                            unsigned h = C[(zz * GDIM + yy) * GDIM + xx];
                            st = h >> 16;
                            cn = h & 0xffffu;
                        }
                    }
                }
                unsigned mc = cn;
#pragma unroll
                for (int o = 1; o < 64; o <<= 1)
                    mc = max(mc, (unsigned)__shfl_xor((int)mc, o, 64));
#pragma unroll 4
                for (unsigned j = 0; j < mc; ++j) {
                    if (j < cn) {
                        float4 p = P[st + j];
                        float t = fmaf(nqx, p.x, fmaf(nqy, p.y, fmaf(nqz, p.z, p.w)));
                        tb = fminf(tb, t);
                    }
                }
            }
#pragma unroll
            for (int o = 1; o < 64; o <<= 1)
                tb = fminf(tb, __shfl_xor(tb, o, 64));
            d2cur = q2 + tb;

            int x0 = max(cx - r, 0), x1 = min(cx + r, GDIM - 1);
            int y0 = max(cy - r, 0), y1 = min(cy + r, GDIM - 1);
            int z0 = max(cz - r, 0), z1 = min(cz + r, GDIM - 1);
            bool full = (x0 == 0 && y0 == 0 && z0 == 0 &&
                         x1 == GDIM - 1 && y1 == GDIM - 1 && z1 == GDIM - 1);
            float mx = fminf(x0 > 0 ? q.x - (lo[0] + x0 * cs[0]) : 1e30f,
                             x1 < GDIM - 1 ? (lo[0] + (x1 + 1) * cs[0]) - q.x : 1e30f);
            float my = fminf(y0 > 0 ? q.y - (lo[1] + y0 * cs[1]) : 1e30f,
                             y1 < GDIM - 1 ? (lo[1] + (y1 + 1) * cs[1]) - q.y : 1e30f);
            float mz = fminf(z0 > 0 ? q.z - (lo[2] + z0 * cs[2]) : 1e30f,
                             z1 < GDIM - 1 ? (lo[2] + (z1 + 1) * cs[2]) - q.z : 1e30f);
            float m = fminf(mx, fminf(my, mz));
            bool done = (m > 0.f) && (m * m * 0.999f >= d2cur);
            if (full || done) break;
        }
        acc += (double)fmaxf(0.f, d2cur);
    }

    __shared__ double sd[4];
    if (lane == 0) sd[wid] = acc;      // acc identical across lanes (post-reduce)
    __syncthreads();
    if (threadIdx.x == 0)
        partialB[blockIdx.x] = sd[0] + sd[1] + sd[2] + sd[3];
}

// ---------------- k6: final reduction ----------------
__global__ __launch_bounds__(256) void k6_final(
    const double* __restrict__ pA, int nA, const double* __restrict__ pB,
    int nB, float* __restrict__ out)
{
    double s = 0.0;
    for (int i = threadIdx.x; i < nA; i += 256) s += pA[i];
    for (int i = threadIdx.x; i < nB; i += 256) s += pB[i];
#pragma unroll
    for (int o = 32; o; o >>= 1) s += __shfl_down(s, o, 64);
    __shared__ double sd[4];
    int wid = threadIdx.x >> 6, lane = threadIdx.x & 63;
    if (lane == 0) sd[wid] = s;
    __syncthreads();
    if (threadIdx.x == 0)
        out[0] = (float)((sd[0] + sd[1] + sd[2] + sd[3]) / (double)BATCH);
}

extern "C" void kernel_launch(void* const* d_in, const int* in_sizes, int n_in,
                              void* d_out, int out_size, void* d_ws, size_t ws_size,
                              hipStream_t stream)
{
    const float* ytrue = (const float*)d_in[0];
    const float* ypred = (const float*)d_in[1];
    int N = in_sizes[0] / (BATCH * 3);          // 8192
    size_t total = (size_t)NG * N;              // 131072
    int nblkA = (int)(total / PA_QPB);          // 8192

    char* ws = (char*)d_ws;
    float4*   sorted  = (float4*)ws;   ws += total * sizeof(float4);     // 2 MB
    unsigned* cnt     = (unsigned*)ws; ws += (size_t)NG * NCELL * 4;     // 2 MB (fill)
    unsigned* sc      = (unsigned*)ws; ws += (size_t)NG * NCELL * 4;     // 2 MB
    uint2*    wlist   = (uint2*)ws;    ws += total * sizeof(uint2);      // 1 MB
    double*   partialA = (double*)ws;  ws += (size_t)nblkA * 8;          // 64 KB
    double*   partialB = (double*)ws;  ws += (size_t)NB_B * 8;           // 16 KB
    float*    bbox    = (float*)ws;    ws += NG * 6 * sizeof(float);
    unsigned* wcount  = (unsigned*)ws; ws += 16;

    k1_bbox_zero<<<NG + 512, 256, 0, stream>>>(ytrue, ypred, N, bbox,
                                               (uint4*)cnt, wcount);
    int ptB = (int)(total / 4 / 256);           // 128 blocks
    k2_hist<<<ptB, 256, 0, stream>>>(ytrue, ypred, N, bbox, cnt);
    k3_scan<<<NG, 1024, 0, stream>>>(cnt, sc);
    k4_scatter<<<ptB, 256, 0, stream>>>(ytrue, ypred, N, bbox, sc, cnt, sorted);
    k5a<<<nblkA, 256, 0, stream>>>(sorted, sc, bbox, N, partialA, wlist, wcount);
    k5b<<<NB_B, 256, 0, stream>>>(sorted, sc, bbox, N, wlist, wcount, partialB);
    k6_final<<<1, 256, 0, stream>>>(partialA, nblkA, partialB, NB_B,
                                    (float*)d_out);
}